// Round 11
// baseline (208.996 us; speedup 1.0000x reference)
//
#include <hip/hip_runtime.h>

// MultiHeadAttention: B=2, S=2048, D_MODEL=1024, H=16, depth=64. FP32 I/O.
// R11 = R10 + widened cvt_all (64B/thread, packed cvtpk, 4096 blocks).
// (1) cvt fp32->bf16 (bf16 materializer -- keeps GEMM re-reads cache-hot, R8
// lesson), (2) QKV GEMM BK=64 + T1 XCD swizzle, (3) flash attention FROZEN at
// R3-verified bytes, (4) O-projection BK=64 TM=64 + T1 XCD swizzle.

typedef unsigned short u16;
typedef unsigned int   u32;
typedef __attribute__((ext_vector_type(8)))  __bf16 bf16x8;   // MFMA A/B fragment
typedef __attribute__((ext_vector_type(8)))  u16    u16x8;
typedef __attribute__((ext_vector_type(4)))  u32    u32x4;
typedef __attribute__((ext_vector_type(4)))  float  f32x4;    // 16x16 C/D
typedef __attribute__((ext_vector_type(16))) float  f32x16;   // 32x32 C/D

#define MFMA16(a,b,c) __builtin_amdgcn_mfma_f32_16x16x32_bf16((a),(b),(c),0,0,0)
#define MFMA32(a,b,c) __builtin_amdgcn_mfma_f32_32x32x16_bf16((a),(b),(c),0,0,0)

__device__ __forceinline__ u16 f2bf(float f) {               // RNE float->bf16
    unsigned int u = __float_as_uint(f);
    return (u16)((u + 0x7FFF + ((u >> 16) & 1)) >> 16);
}
__device__ __forceinline__ u32 cvtpk(float a, float b) {     // 2xfp32 -> packed bf16 (RNE)
    u32 d;
    asm("v_cvt_pk_bf16_f32 %0, %1, %2" : "=v"(d) : "v"(a), "v"(b));
    return d;
}
__device__ __forceinline__ void gl2lds16(const void* g, void* l) {  // async 16B global->LDS
    __builtin_amdgcn_global_load_lds((const __attribute__((address_space(1))) unsigned int*)g,
                                     (__attribute__((address_space(3))) unsigned int*)l, 16, 0, 0);
}

// ---------------------------------------------------------------------------
// fused fp32 -> bf16 convert, 64B/thread (16 floats), exact 4096-block grid.
// blocks [0,3072): Q/K/V (1024 each); [3072,4096): W0..W3 (256 each).
// cvtpk = RNE = f2bf -> bit-identical outputs vs the 32B/thread version.
// ---------------------------------------------------------------------------
__global__ __launch_bounds__(256)
void cvt_all(const float* __restrict__ Q, const float* __restrict__ K, const float* __restrict__ V,
             const float* __restrict__ W0, const float* __restrict__ W1,
             const float* __restrict__ W2, const float* __restrict__ W3,
             u16* __restrict__ oq, u16* __restrict__ ok, u16* __restrict__ ov,
             u16* __restrict__ o0, u16* __restrict__ o1, u16* __restrict__ o2, u16* __restrict__ o3)
{
    const int bx = blockIdx.x;
    const float* s; u16* d; int local;
    if (bx < 3072) {
        int t = bx >> 10; local = bx & 1023;
        s = (t == 0) ? Q : (t == 1) ? K : V;
        d = (t == 0) ? oq : (t == 1) ? ok : ov;
    } else {
        int t = (bx - 3072) >> 8; local = (bx - 3072) & 255;
        s = (t == 0) ? W0 : (t == 1) ? W1 : (t == 2) ? W2 : W3;
        d = (t == 0) ? o0 : (t == 1) ? o1 : (t == 2) ? o2 : o3;
    }
    size_t i = ((size_t)local * 256 + threadIdx.x) * 16;
    f32x4 a = *(const f32x4*)(s + i),      b = *(const f32x4*)(s + i + 4);
    f32x4 c = *(const f32x4*)(s + i + 8),  e = *(const f32x4*)(s + i + 12);
    u32x4 lo = { cvtpk(a[0], a[1]), cvtpk(a[2], a[3]), cvtpk(b[0], b[1]), cvtpk(b[2], b[3]) };
    u32x4 hi = { cvtpk(c[0], c[1]), cvtpk(c[2], c[3]), cvtpk(e[0], e[1]), cvtpk(e[2], e[3]) };
    *(u32x4*)(d + i)     = lo;
    *(u32x4*)(d + i + 8) = hi;
}

// ---------------------------------------------------------------------------
// BT-GEMM, BK=64 (m97 geometry): C[m,n] = scale*(sum_k A[m,k]*W[n,k] + bias).
// TM x 128 tile. Staging mirrors the attn-verified [rows][64] chunk swizzle:
// LDS chunk kc of row r holds global chunk kc^(r&7); reader fetches c^(r&7).
// k ascending in all variants -> bit-identical C vs the BK=32 original.
// LAYOUT: 0 -> qh/kh (B,H,S,64) bf16; 2 -> (M,N) fp32; 3 -> vt (B,H,64,S) bf16.
// ---------------------------------------------------------------------------
template<int LAYOUT, int TM>
__device__ __forceinline__ void gemm_body64(const u16* __restrict__ A, const u16* __restrict__ W,
                                            const float* __restrict__ bias, void* __restrict__ outv,
                                            u16* S, int m0, int n0, float scale)
{
    constexpr int MI = TM / 32;
    u16* As = S;                               // [TM][64] bf16
    u16* Bs = S + TM * 64;                     // [128][64] bf16
    const int tid  = threadIdx.x;
    const int wave = tid >> 6, lane = tid & 63;
    const int quad = lane >> 4, l16 = lane & 15;
    const int wr = (wave >> 1) * (TM / 2), wc = (wave & 1) * 64;
    const int s7 = l16 & 7;                    // row&7 for all frag rows

    f32x4 acc[MI][4] = {};

    for (int k0 = 0; k0 < 1024; k0 += 64) {
        __syncthreads();
        #pragma unroll
        for (int t = 0; t < MI; t++) {         // A: TM rows x 8 chunks
            int idx = t * 256 + tid;
            int r = idx >> 3, c = idx & 7;
            gl2lds16(A + (size_t)(m0 + r) * 1024 + k0 + ((c ^ (r & 7)) * 8), As + idx * 8);
        }
        #pragma unroll
        for (int t = 0; t < 4; t++) {          // B: 128 rows x 8 chunks = 1024
            int idx = t * 256 + tid;
            int r = idx >> 3, c = idx & 7;
            gl2lds16(W + (size_t)(n0 + r) * 1024 + k0 + ((c ^ (r & 7)) * 8), Bs + idx * 8);
        }
        __syncthreads();
        #pragma unroll
        for (int ks = 0; ks < 2; ks++) {       // two k=32 sub-steps, ascending k
            const int sw = (ks * 4 + quad) ^ s7;
            bf16x8 af[MI], bfr[4];
            #pragma unroll
            for (int i = 0; i < MI; i++)
                af[i] = *(const bf16x8*)(As + (wr + i * 16 + l16) * 64 + sw * 8);
            #pragma unroll
            for (int j = 0; j < 4; j++)
                bfr[j] = *(const bf16x8*)(Bs + (wc + j * 16 + l16) * 64 + sw * 8);
            #pragma unroll
            for (int i = 0; i < MI; i++)
                #pragma unroll
                for (int j = 0; j < 4; j++)
                    acc[i][j] = MFMA16(af[i], bfr[j], acc[i][j]);
        }
    }

    if (LAYOUT == 2) {          // fp32 direct stores (gemm_o)
        float bv[4];
        #pragma unroll
        for (int j = 0; j < 4; j++) bv[j] = bias[n0 + wc + j * 16 + l16];
        #pragma unroll
        for (int i = 0; i < MI; i++)
            #pragma unroll
            for (int j = 0; j < 4; j++) {
                int gn = n0 + wc + j * 16 + l16;
                #pragma unroll
                for (int r = 0; r < 4; r++) {
                    int gm = m0 + wr + i * 16 + quad * 4 + r;
                    ((float*)outv)[(size_t)gm * 1024 + gn] = acc[i][j][r] + bv[j];
                }
            }
    } else {                    // bf16 layouts: LDS-bounced coalesced epilogue
        float bv[4], bm[MI][4];
        if (LAYOUT == 0) {
            #pragma unroll
            for (int j = 0; j < 4; j++) bv[j] = bias[n0 + wc + j * 16 + l16];
        } else {
            #pragma unroll
            for (int i = 0; i < MI; i++)
                #pragma unroll
                for (int r = 0; r < 4; r++) bm[i][r] = bias[m0 + wr + i * 16 + quad * 4 + r];
        }
        __syncthreads();                       // K-loop readers of S are done
        u16* WR = S + wave * (16 * 68);        // per-wave bounce region, pitch 68
        #pragma unroll
        for (int i = 0; i < MI; i++) {
            #pragma unroll
            for (int j = 0; j < 4; j++)
                #pragma unroll
                for (int r = 0; r < 4; r++) {
                    float v = (acc[i][j][r] + (LAYOUT == 0 ? bv[j] : bm[i][r])) * scale;
                    WR[(quad * 4 + r) * 68 + j * 16 + l16] = f2bf(v);
                }
            int gm0 = m0 + wr + i * 16, gn0 = n0 + wc;
            size_t gb;
            if (LAYOUT == 0) gb = (((size_t)(gm0 >> 11) * 16 + (gn0 >> 6)) * 2048 + (gm0 & 2047)) * 64;
            else             gb = (((size_t)(gn0 >> 11) * 16 + (gm0 >> 6)) * 64 + (gm0 & 63)) * 2048 + (gn0 & 2047);
            #pragma unroll
            for (int st = 0; st < 2; st++) {
                int chunk = st * 64 + lane;
                int row = chunk >> 3, c8 = chunk & 7;
                u16x8 v = *(const u16x8*)(WR + row * 68 + c8 * 8);
                size_t ga = (LAYOUT == 0) ? gb + row * 64 + c8 * 8 : gb + (size_t)row * 2048 + c8 * 8;
                *(u16x8*)((u16*)outv + ga) = v;
            }
        }
    }
}

#define CST 0.18033688011112042f   // log2(e)/sqrt(64), folded into qh

__global__ __launch_bounds__(256, 3)
void gemm_qkv(const u16* __restrict__ Qb, const u16* __restrict__ Kb, const u16* __restrict__ Vb,
              const u16* __restrict__ Wq, const u16* __restrict__ Wk, const u16* __restrict__ Wv,
              const float* __restrict__ bq, const float* __restrict__ bk, const float* __restrict__ bv,
              u16* __restrict__ qh, u16* __restrict__ kh, u16* __restrict__ vt)
{
    __shared__ __align__(16) u16 S[128 * 64 * 2];    // 32KB: A + B tiles

    // T1 XCD swizzle: 768 blocks % 8 == 0 -> bijective. Each XCD owns 96
    // consecutive work ids (~12 A-panels + 8 W-panels ~= 5MB, mostly L2-local)
    // instead of round-robin touching every panel. (verified R10: total -9.4us)
    const int lid = blockIdx.x + 8 * (blockIdx.y + 32 * blockIdx.z);
    const int w   = (lid & 7) * 96 + (lid >> 3);
    const int bx  = w & 7, by = (w >> 3) & 31, bz = w >> 8;

    if (bz < 2) {
        gemm_body64<0, 128>(bz == 0 ? Qb : Kb, bz == 0 ? Wq : Wk, bz == 0 ? bq : bk,
                            bz == 0 ? qh : kh, S, by * 128, bx * 128,
                            bz == 0 ? CST : 1.0f);
    } else {
        gemm_body64<3, 128>(Wv, Vb, bv, vt, S, bx * 128, by * 128, 1.0f);
    }
}

__global__ __launch_bounds__(256, 2)
void gemm_o(const u16* __restrict__ A, const u16* __restrict__ W,
            const float* __restrict__ bias, float* __restrict__ out)
{
    __shared__ __align__(16) u16 S[64 * 64 + 128 * 64];   // 24KB: A(64x64) + B(128x64)

    // T1 XCD swizzle: 512 blocks % 8 == 0 -> bijective. Each XCD owns 64
    // consecutive ids = 8 y-panels x all 8 x -> ~3MB working set, L2-fits.
    const int lid = blockIdx.x + 8 * blockIdx.y;
    const int w   = (lid & 7) * 64 + (lid >> 3);
    const int bx  = w & 7, by = w >> 3;

    gemm_body64<2, 64>(A, W, bias, out, S, by * 64, bx * 128, 1.0f);
}

// ---------------------------------------------------------------------------
// Flash attention — FROZEN R3-verified bytes. kv-tile 256, single-buffer,
// two-barrier template, T1 XCD swizzle. Do not perturb the instruction stream:
// R2/R4/R5 showed schedule-sensitive failures on any compute reordering.
// ---------------------------------------------------------------------------
__global__ __launch_bounds__(256, 2)
void attn_fused(const u16* __restrict__ qh, const u16* __restrict__ kh,
                const u16* __restrict__ vt, u16* __restrict__ out)
{
    __shared__ __align__(16) u16 Ks[256 * 64];        // [kv][d], chunk-swizzled, 32KB
    __shared__ __align__(16) u16 Vs[64 * 256];        // [d][kv], chunk-swizzled, 32KB

    const int tid  = threadIdx.x;
    const int wave = tid >> 6, lane = tid & 63;
    const int l31 = lane & 31, h = lane >> 5;

    // T1 XCD swizzle: lid in [0,512), w = (lid%8)*64 + lid/8 (bijective, 512%8==0)
    const int lid = blockIdx.x + 16 * (blockIdx.y + 16 * blockIdx.z);
    const int w   = (lid & 7) * 64 + (lid >> 3);
    const int q0  = (w & 15) * 128;
    const int hh  = (w >> 4) & 15, b = w >> 8;

    const size_t head = (size_t)(b * 16 + hh);
    const u16* qh_h = qh + head * (2048 * 64);
    const u16* kh_h = kh + head * (2048 * 64);
    const u16* vt_h = vt + head * (64 * 2048);

    // Q as B-operand (n = q = lane&31, k = h*8+j)
    bf16x8 qf[4];
    #pragma unroll
    for (int ks = 0; ks < 4; ks++)
        qf[ks] = *(const bf16x8*)(qh_h + (size_t)(q0 + wave * 32 + l31) * 64 + ks * 16 + h * 8);

    const u32 one2 = 0x3F803F80u;                     // two bf16 1.0
    const u32x4 onesw = {one2, one2, one2, one2};
    const bf16x8 onesf = __builtin_bit_cast(bf16x8, onesw);

    f32x16 oacc[2] = {};
    f32x16 lacc = {};                                 // all regs -> l(q) via ones-MFMA

    for (int kt = 0; kt < 8; kt++) {
        const int kv0 = kt * 256;
        __syncthreads();
        #pragma unroll
        for (int it = 0; it < 8; it++) {
            int idx = it * 256 + tid;                 // 2048 chunks per tile
            int kr = idx >> 3, kc = idx & 7;
            gl2lds16(kh_h + (size_t)(kv0 + kr) * 64 + ((kc ^ (kr & 7)) * 8), Ks + idx * 8);
            int vr = idx >> 5, vc = idx & 31;
            gl2lds16(vt_h + (size_t)vr * 2048 + kv0 + ((vc ^ (vr & 15)) * 8), Vs + idx * 8);
        }
        __syncthreads();

        #pragma unroll
        for (int mt = 0; mt < 8; mt++) {              // 32-kv sub-tiles
            f32x16 sacc = {};
            #pragma unroll
            for (int ks = 0; ks < 4; ks++) {          // S^T: A = K (m=kv), B = Q
                int row = mt * 32 + l31;
                bf16x8 kf = *(const bf16x8*)(Ks + row * 64 + (((ks * 2 + h) ^ (l31 & 7)) * 8));
                sacc = MFMA32(kf, qf[ks], sacc);
            }
            u32 P[4][2];                              // p = exp2(s); packed pairs
            #pragma unroll
            for (int g = 0; g < 4; g++) {
                P[g][0] = cvtpk(__builtin_amdgcn_exp2f(sacc[g * 4 + 0]),
                                __builtin_amdgcn_exp2f(sacc[g * 4 + 1]));
                P[g][1] = cvtpk(__builtin_amdgcn_exp2f(sacc[g * 4 + 2]),
                                __builtin_amdgcn_exp2f(sacc[g * 4 + 3]));
            }
            #pragma unroll
            for (int c16 = 0; c16 < 2; c16++) {       // two k=16 chunks
                u32 x0 = P[2 * c16][0], y0 = P[2 * c16 + 1][0];
                u32 x1 = P[2 * c16][1], y1 = P[2 * c16 + 1][1];
                asm volatile("v_permlane32_swap_b32 %0, %1" : "+v"(x0), "+v"(y0));
                asm volatile("v_permlane32_swap_b32 %0, %1" : "+v"(x1), "+v"(y1));
                u32x4 bw = {x0, x1, y0, y1};          // B-frag: n=q, k=kv
                bf16x8 pB = __builtin_bit_cast(bf16x8, bw);
                lacc = MFMA32(onesf, pB, lacc);       // l(q) += column sums of P
                int c = mt * 4 + c16 * 2 + h;
                #pragma unroll
                for (int dt = 0; dt < 2; dt++) {      // O^T: A = V^T (m=d), B = P^T
                    int d = dt * 32 + l31;
                    bf16x8 vf = *(const bf16x8*)(Vs + d * 256 + ((c ^ (l31 & 15)) * 8));
                    oacc[dt] = MFMA32(vf, pB, oacc[dt]);
                }
            }
        }
    }

    float inv = 1.0f / lacc[0];                       // every lane holds full l(q)

    // O^T: col = q = lane&31, row = d = dt*32 + 8g + 4h + r
    size_t ob = ((size_t)(b * 2048 + q0 + wave * 32 + l31)) * 1024 + hh * 64;
    #pragma unroll
    for (int dt = 0; dt < 2; dt++)
        #pragma unroll
        for (int g = 0; g < 4; g++) {
            int d0 = dt * 32 + 8 * g + 4 * h;
            *(u32*)((u16*)out + ob + d0)     = cvtpk(oacc[dt][g * 4 + 0] * inv, oacc[dt][g * 4 + 1] * inv);
            *(u32*)((u16*)out + ob + d0 + 2) = cvtpk(oacc[dt][g * 4 + 2] * inv, oacc[dt][g * 4 + 3] * inv);
        }
}

extern "C" void kernel_launch(void* const* d_in, const int* in_sizes, int n_in,
                              void* d_out, int out_size, void* d_ws, size_t ws_size,
                              hipStream_t stream)
{
    const float* Q   = (const float*)d_in[0];
    const float* Kin = (const float*)d_in[1];
    const float* V   = (const float*)d_in[2];
    const float* Wq  = (const float*)d_in[3];
    const float* bq  = (const float*)d_in[4];
    const float* Wk  = (const float*)d_in[5];
    const float* bk  = (const float*)d_in[6];
    const float* Wv  = (const float*)d_in[7];
    const float* bv  = (const float*)d_in[8];
    const float* Wo  = (const float*)d_in[9];
    const float* bo  = (const float*)d_in[10];

    const size_t TS = (size_t)2 * 2048 * 1024;
    const size_t WS = (size_t)1024 * 1024;
    u16* Qb  = (u16*)d_ws;
    u16* Kb  = Qb + TS;
    u16* Vb  = Kb + TS;
    u16* qh  = Vb + TS;
    u16* kh  = qh + TS;
    u16* vt  = kh + TS;
    u16* Wqb = vt + TS;
    u16* Wkb = Wqb + WS;
    u16* Wvb = Wkb + WS;
    u16* Wob = Wvb + WS;
    u16* at  = Qb;   // Qb dead after gemm_qkv

    cvt_all<<<dim3(4096), 256, 0, stream>>>(Q, Kin, V, Wq, Wk, Wv, Wo,
                                            Qb, Kb, Vb, Wqb, Wkb, Wvb, Wob);
    gemm_qkv<<<dim3(8, 32, 3), 256, 0, stream>>>(Qb, Kb, Vb, Wqb, Wkb, Wvb, bq, bk, bv, qh, kh, vt);
    attn_fused<<<dim3(16, 16, 2), 256, 0, stream>>>(qh, kh, vt, at);
    gemm_o<<<dim3(8, 64), 256, 0, stream>>>(at, Wob, bo, (float*)d_out);
}

// Round 12
// 200.861 us; speedup vs baseline: 1.0405x; 1.0405x over previous
//
#include <hip/hip_runtime.h>

// MultiHeadAttention: B=2, S=2048, D_MODEL=1024, H=16, depth=64. FP32 I/O.
// R12 = exact re-land of the session-best R10 (202.7 us verified). R11's cvt
// widening was noise-to-negative (attn clock-drift band +-6% confounded it).
// (1) cvt fp32->bf16, 32B/thread, 8192 blocks (bf16 materializer -- keeps GEMM
// re-reads cache-hot, R8 lesson), (2) QKV GEMM BK=64 + T1 XCD swizzle,
// (3) flash attention FROZEN at R3-verified bytes, (4) O-projection BK=64
// TM=64 + T1 XCD swizzle.

typedef unsigned short u16;
typedef unsigned int   u32;
typedef __attribute__((ext_vector_type(8)))  __bf16 bf16x8;   // MFMA A/B fragment
typedef __attribute__((ext_vector_type(8)))  u16    u16x8;
typedef __attribute__((ext_vector_type(4)))  u32    u32x4;
typedef __attribute__((ext_vector_type(4)))  float  f32x4;    // 16x16 C/D
typedef __attribute__((ext_vector_type(16))) float  f32x16;   // 32x32 C/D

#define MFMA16(a,b,c) __builtin_amdgcn_mfma_f32_16x16x32_bf16((a),(b),(c),0,0,0)
#define MFMA32(a,b,c) __builtin_amdgcn_mfma_f32_32x32x16_bf16((a),(b),(c),0,0,0)

__device__ __forceinline__ u16 f2bf(float f) {               // RNE float->bf16
    unsigned int u = __float_as_uint(f);
    return (u16)((u + 0x7FFF + ((u >> 16) & 1)) >> 16);
}
__device__ __forceinline__ u32 cvtpk(float a, float b) {     // 2xfp32 -> packed bf16 (RNE)
    u32 d;
    asm("v_cvt_pk_bf16_f32 %0, %1, %2" : "=v"(d) : "v"(a), "v"(b));
    return d;
}
__device__ __forceinline__ void gl2lds16(const void* g, void* l) {  // async 16B global->LDS
    __builtin_amdgcn_global_load_lds((const __attribute__((address_space(1))) unsigned int*)g,
                                     (__attribute__((address_space(3))) unsigned int*)l, 16, 0, 0);
}

// ---------------------------------------------------------------------------
// fused fp32 -> bf16 convert, exact 8192-block grid.
// blocks [0,6144): Q/K/V (2048 each); [6144,8192): W0..W3 (512 each).
// ---------------------------------------------------------------------------
__global__ __launch_bounds__(256)
void cvt_all(const float* __restrict__ Q, const float* __restrict__ K, const float* __restrict__ V,
             const float* __restrict__ W0, const float* __restrict__ W1,
             const float* __restrict__ W2, const float* __restrict__ W3,
             u16* __restrict__ oq, u16* __restrict__ ok, u16* __restrict__ ov,
             u16* __restrict__ o0, u16* __restrict__ o1, u16* __restrict__ o2, u16* __restrict__ o3)
{
    const int bx = blockIdx.x;
    const float* s; u16* d; int local;
    if (bx < 6144) {
        int t = bx >> 11; local = bx & 2047;
        s = (t == 0) ? Q : (t == 1) ? K : V;
        d = (t == 0) ? oq : (t == 1) ? ok : ov;
    } else {
        int t = (bx - 6144) >> 9; local = (bx - 6144) & 511;
        s = (t == 0) ? W0 : (t == 1) ? W1 : (t == 2) ? W2 : W3;
        d = (t == 0) ? o0 : (t == 1) ? o1 : (t == 2) ? o2 : o3;
    }
    size_t i = ((size_t)local * 256 + threadIdx.x) * 8;
    f32x4 lo = *(const f32x4*)(s + i), hi = *(const f32x4*)(s + i + 4);
    u16x8 v;
    #pragma unroll
    for (int t = 0; t < 4; t++) { v[t] = f2bf(lo[t]); v[4 + t] = f2bf(hi[t]); }
    *(u16x8*)(d + i) = v;
}

// ---------------------------------------------------------------------------
// BT-GEMM, BK=64 (m97 geometry): C[m,n] = scale*(sum_k A[m,k]*W[n,k] + bias).
// TM x 128 tile. Staging mirrors the attn-verified [rows][64] chunk swizzle:
// LDS chunk kc of row r holds global chunk kc^(r&7); reader fetches c^(r&7).
// k ascending in all variants -> bit-identical C vs the BK=32 original.
// LAYOUT: 0 -> qh/kh (B,H,S,64) bf16; 2 -> (M,N) fp32; 3 -> vt (B,H,64,S) bf16.
// ---------------------------------------------------------------------------
template<int LAYOUT, int TM>
__device__ __forceinline__ void gemm_body64(const u16* __restrict__ A, const u16* __restrict__ W,
                                            const float* __restrict__ bias, void* __restrict__ outv,
                                            u16* S, int m0, int n0, float scale)
{
    constexpr int MI = TM / 32;
    u16* As = S;                               // [TM][64] bf16
    u16* Bs = S + TM * 64;                     // [128][64] bf16
    const int tid  = threadIdx.x;
    const int wave = tid >> 6, lane = tid & 63;
    const int quad = lane >> 4, l16 = lane & 15;
    const int wr = (wave >> 1) * (TM / 2), wc = (wave & 1) * 64;
    const int s7 = l16 & 7;                    // row&7 for all frag rows

    f32x4 acc[MI][4] = {};

    for (int k0 = 0; k0 < 1024; k0 += 64) {
        __syncthreads();
        #pragma unroll
        for (int t = 0; t < MI; t++) {         // A: TM rows x 8 chunks
            int idx = t * 256 + tid;
            int r = idx >> 3, c = idx & 7;
            gl2lds16(A + (size_t)(m0 + r) * 1024 + k0 + ((c ^ (r & 7)) * 8), As + idx * 8);
        }
        #pragma unroll
        for (int t = 0; t < 4; t++) {          // B: 128 rows x 8 chunks = 1024
            int idx = t * 256 + tid;
            int r = idx >> 3, c = idx & 7;
            gl2lds16(W + (size_t)(n0 + r) * 1024 + k0 + ((c ^ (r & 7)) * 8), Bs + idx * 8);
        }
        __syncthreads();
        #pragma unroll
        for (int ks = 0; ks < 2; ks++) {       // two k=32 sub-steps, ascending k
            const int sw = (ks * 4 + quad) ^ s7;
            bf16x8 af[MI], bfr[4];
            #pragma unroll
            for (int i = 0; i < MI; i++)
                af[i] = *(const bf16x8*)(As + (wr + i * 16 + l16) * 64 + sw * 8);
            #pragma unroll
            for (int j = 0; j < 4; j++)
                bfr[j] = *(const bf16x8*)(Bs + (wc + j * 16 + l16) * 64 + sw * 8);
            #pragma unroll
            for (int i = 0; i < MI; i++)
                #pragma unroll
                for (int j = 0; j < 4; j++)
                    acc[i][j] = MFMA16(af[i], bfr[j], acc[i][j]);
        }
    }

    if (LAYOUT == 2) {          // fp32 direct stores (gemm_o)
        float bv[4];
        #pragma unroll
        for (int j = 0; j < 4; j++) bv[j] = bias[n0 + wc + j * 16 + l16];
        #pragma unroll
        for (int i = 0; i < MI; i++)
            #pragma unroll
            for (int j = 0; j < 4; j++) {
                int gn = n0 + wc + j * 16 + l16;
                #pragma unroll
                for (int r = 0; r < 4; r++) {
                    int gm = m0 + wr + i * 16 + quad * 4 + r;
                    ((float*)outv)[(size_t)gm * 1024 + gn] = acc[i][j][r] + bv[j];
                }
            }
    } else {                    // bf16 layouts: LDS-bounced coalesced epilogue
        float bv[4], bm[MI][4];
        if (LAYOUT == 0) {
            #pragma unroll
            for (int j = 0; j < 4; j++) bv[j] = bias[n0 + wc + j * 16 + l16];
        } else {
            #pragma unroll
            for (int i = 0; i < MI; i++)
                #pragma unroll
                for (int r = 0; r < 4; r++) bm[i][r] = bias[m0 + wr + i * 16 + quad * 4 + r];
        }
        __syncthreads();                       // K-loop readers of S are done
        u16* WR = S + wave * (16 * 68);        // per-wave bounce region, pitch 68
        #pragma unroll
        for (int i = 0; i < MI; i++) {
            #pragma unroll
            for (int j = 0; j < 4; j++)
                #pragma unroll
                for (int r = 0; r < 4; r++) {
                    float v = (acc[i][j][r] + (LAYOUT == 0 ? bv[j] : bm[i][r])) * scale;
                    WR[(quad * 4 + r) * 68 + j * 16 + l16] = f2bf(v);
                }
            int gm0 = m0 + wr + i * 16, gn0 = n0 + wc;
            size_t gb;
            if (LAYOUT == 0) gb = (((size_t)(gm0 >> 11) * 16 + (gn0 >> 6)) * 2048 + (gm0 & 2047)) * 64;
            else             gb = (((size_t)(gn0 >> 11) * 16 + (gm0 >> 6)) * 64 + (gm0 & 63)) * 2048 + (gn0 & 2047);
            #pragma unroll
            for (int st = 0; st < 2; st++) {
                int chunk = st * 64 + lane;
                int row = chunk >> 3, c8 = chunk & 7;
                u16x8 v = *(const u16x8*)(WR + row * 68 + c8 * 8);
                size_t ga = (LAYOUT == 0) ? gb + row * 64 + c8 * 8 : gb + (size_t)row * 2048 + c8 * 8;
                *(u16x8*)((u16*)outv + ga) = v;
            }
        }
    }
}

#define CST 0.18033688011112042f   // log2(e)/sqrt(64), folded into qh

__global__ __launch_bounds__(256, 3)
void gemm_qkv(const u16* __restrict__ Qb, const u16* __restrict__ Kb, const u16* __restrict__ Vb,
              const u16* __restrict__ Wq, const u16* __restrict__ Wk, const u16* __restrict__ Wv,
              const float* __restrict__ bq, const float* __restrict__ bk, const float* __restrict__ bv,
              u16* __restrict__ qh, u16* __restrict__ kh, u16* __restrict__ vt)
{
    __shared__ __align__(16) u16 S[128 * 64 * 2];    // 32KB: A + B tiles

    // T1 XCD swizzle: 768 blocks % 8 == 0 -> bijective. Each XCD owns 96
    // consecutive work ids (~12 A-panels + 8 W-panels ~= 5MB, mostly L2-local)
    // instead of round-robin touching every panel. (verified R10: total -9.4us)
    const int lid = blockIdx.x + 8 * (blockIdx.y + 32 * blockIdx.z);
    const int w   = (lid & 7) * 96 + (lid >> 3);
    const int bx  = w & 7, by = (w >> 3) & 31, bz = w >> 8;

    if (bz < 2) {
        gemm_body64<0, 128>(bz == 0 ? Qb : Kb, bz == 0 ? Wq : Wk, bz == 0 ? bq : bk,
                            bz == 0 ? qh : kh, S, by * 128, bx * 128,
                            bz == 0 ? CST : 1.0f);
    } else {
        gemm_body64<3, 128>(Wv, Vb, bv, vt, S, bx * 128, by * 128, 1.0f);
    }
}

__global__ __launch_bounds__(256, 2)
void gemm_o(const u16* __restrict__ A, const u16* __restrict__ W,
            const float* __restrict__ bias, float* __restrict__ out)
{
    __shared__ __align__(16) u16 S[64 * 64 + 128 * 64];   // 24KB: A(64x64) + B(128x64)

    // T1 XCD swizzle: 512 blocks % 8 == 0 -> bijective. Each XCD owns 64
    // consecutive ids = 8 y-panels x all 8 x -> ~3MB working set, L2-fits.
    const int lid = blockIdx.x + 8 * blockIdx.y;
    const int w   = (lid & 7) * 64 + (lid >> 3);
    const int bx  = w & 7, by = w >> 3;

    gemm_body64<2, 64>(A, W, bias, out, S, by * 64, bx * 128, 1.0f);
}

// ---------------------------------------------------------------------------
// Flash attention — FROZEN R3-verified bytes. kv-tile 256, single-buffer,
// two-barrier template, T1 XCD swizzle. Do not perturb the instruction stream:
// R2/R4/R5 showed schedule-sensitive failures on any compute reordering.
// ---------------------------------------------------------------------------
__global__ __launch_bounds__(256, 2)
void attn_fused(const u16* __restrict__ qh, const u16* __restrict__ kh,
                const u16* __restrict__ vt, u16* __restrict__ out)
{
    __shared__ __align__(16) u16 Ks[256 * 64];        // [kv][d], chunk-swizzled, 32KB
    __shared__ __align__(16) u16 Vs[64 * 256];        // [d][kv], chunk-swizzled, 32KB

    const int tid  = threadIdx.x;
    const int wave = tid >> 6, lane = tid & 63;
    const int l31 = lane & 31, h = lane >> 5;

    // T1 XCD swizzle: lid in [0,512), w = (lid%8)*64 + lid/8 (bijective, 512%8==0)
    const int lid = blockIdx.x + 16 * (blockIdx.y + 16 * blockIdx.z);
    const int w   = (lid & 7) * 64 + (lid >> 3);
    const int q0  = (w & 15) * 128;
    const int hh  = (w >> 4) & 15, b = w >> 8;

    const size_t head = (size_t)(b * 16 + hh);
    const u16* qh_h = qh + head * (2048 * 64);
    const u16* kh_h = kh + head * (2048 * 64);
    const u16* vt_h = vt + head * (64 * 2048);

    // Q as B-operand (n = q = lane&31, k = h*8+j)
    bf16x8 qf[4];
    #pragma unroll
    for (int ks = 0; ks < 4; ks++)
        qf[ks] = *(const bf16x8*)(qh_h + (size_t)(q0 + wave * 32 + l31) * 64 + ks * 16 + h * 8);

    const u32 one2 = 0x3F803F80u;                     // two bf16 1.0
    const u32x4 onesw = {one2, one2, one2, one2};
    const bf16x8 onesf = __builtin_bit_cast(bf16x8, onesw);

    f32x16 oacc[2] = {};
    f32x16 lacc = {};                                 // all regs -> l(q) via ones-MFMA

    for (int kt = 0; kt < 8; kt++) {
        const int kv0 = kt * 256;
        __syncthreads();
        #pragma unroll
        for (int it = 0; it < 8; it++) {
            int idx = it * 256 + tid;                 // 2048 chunks per tile
            int kr = idx >> 3, kc = idx & 7;
            gl2lds16(kh_h + (size_t)(kv0 + kr) * 64 + ((kc ^ (kr & 7)) * 8), Ks + idx * 8);
            int vr = idx >> 5, vc = idx & 31;
            gl2lds16(vt_h + (size_t)vr * 2048 + kv0 + ((vc ^ (vr & 15)) * 8), Vs + idx * 8);
        }
        __syncthreads();

        #pragma unroll
        for (int mt = 0; mt < 8; mt++) {              // 32-kv sub-tiles
            f32x16 sacc = {};
            #pragma unroll
            for (int ks = 0; ks < 4; ks++) {          // S^T: A = K (m=kv), B = Q
                int row = mt * 32 + l31;
                bf16x8 kf = *(const bf16x8*)(Ks + row * 64 + (((ks * 2 + h) ^ (l31 & 7)) * 8));
                sacc = MFMA32(kf, qf[ks], sacc);
            }
            u32 P[4][2];                              // p = exp2(s); packed pairs
            #pragma unroll
            for (int g = 0; g < 4; g++) {
                P[g][0] = cvtpk(__builtin_amdgcn_exp2f(sacc[g * 4 + 0]),
                                __builtin_amdgcn_exp2f(sacc[g * 4 + 1]));
                P[g][1] = cvtpk(__builtin_amdgcn_exp2f(sacc[g * 4 + 2]),
                                __builtin_amdgcn_exp2f(sacc[g * 4 + 3]));
            }
            #pragma unroll
            for (int c16 = 0; c16 < 2; c16++) {       // two k=16 chunks
                u32 x0 = P[2 * c16][0], y0 = P[2 * c16 + 1][0];
                u32 x1 = P[2 * c16][1], y1 = P[2 * c16 + 1][1];
                asm volatile("v_permlane32_swap_b32 %0, %1" : "+v"(x0), "+v"(y0));
                asm volatile("v_permlane32_swap_b32 %0, %1" : "+v"(x1), "+v"(y1));
                u32x4 bw = {x0, x1, y0, y1};          // B-frag: n=q, k=kv
                bf16x8 pB = __builtin_bit_cast(bf16x8, bw);
                lacc = MFMA32(onesf, pB, lacc);       // l(q) += column sums of P
                int c = mt * 4 + c16 * 2 + h;
                #pragma unroll
                for (int dt = 0; dt < 2; dt++) {      // O^T: A = V^T (m=d), B = P^T
                    int d = dt * 32 + l31;
                    bf16x8 vf = *(const bf16x8*)(Vs + d * 256 + ((c ^ (l31 & 15)) * 8));
                    oacc[dt] = MFMA32(vf, pB, oacc[dt]);
                }
            }
        }
    }

    float inv = 1.0f / lacc[0];                       // every lane holds full l(q)

    // O^T: col = q = lane&31, row = d = dt*32 + 8g + 4h + r
    size_t ob = ((size_t)(b * 2048 + q0 + wave * 32 + l31)) * 1024 + hh * 64;
    #pragma unroll
    for (int dt = 0; dt < 2; dt++)
        #pragma unroll
        for (int g = 0; g < 4; g++) {
            int d0 = dt * 32 + 8 * g + 4 * h;
            *(u32*)((u16*)out + ob + d0)     = cvtpk(oacc[dt][g * 4 + 0] * inv, oacc[dt][g * 4 + 1] * inv);
            *(u32*)((u16*)out + ob + d0 + 2) = cvtpk(oacc[dt][g * 4 + 2] * inv, oacc[dt][g * 4 + 3] * inv);
        }
}

extern "C" void kernel_launch(void* const* d_in, const int* in_sizes, int n_in,
                              void* d_out, int out_size, void* d_ws, size_t ws_size,
                              hipStream_t stream)
{
    const float* Q   = (const float*)d_in[0];
    const float* Kin = (const float*)d_in[1];
    const float* V   = (const float*)d_in[2];
    const float* Wq  = (const float*)d_in[3];
    const float* bq  = (const float*)d_in[4];
    const float* Wk  = (const float*)d_in[5];
    const float* bk  = (const float*)d_in[6];
    const float* Wv  = (const float*)d_in[7];
    const float* bv  = (const float*)d_in[8];
    const float* Wo  = (const float*)d_in[9];
    const float* bo  = (const float*)d_in[10];

    const size_t TS = (size_t)2 * 2048 * 1024;
    const size_t WS = (size_t)1024 * 1024;
    u16* Qb  = (u16*)d_ws;
    u16* Kb  = Qb + TS;
    u16* Vb  = Kb + TS;
    u16* qh  = Vb + TS;
    u16* kh  = qh + TS;
    u16* vt  = kh + TS;
    u16* Wqb = vt + TS;
    u16* Wkb = Wqb + WS;
    u16* Wvb = Wkb + WS;
    u16* Wob = Wvb + WS;
    u16* at  = Qb;   // Qb dead after gemm_qkv

    cvt_all<<<dim3(8192), 256, 0, stream>>>(Q, Kin, V, Wq, Wk, Wv, Wo,
                                            Qb, Kb, Vb, Wqb, Wkb, Wvb, Wob);
    gemm_qkv<<<dim3(8, 32, 3), 256, 0, stream>>>(Qb, Kb, Vb, Wqb, Wkb, Wvb, bq, bk, bv, qh, kh, vt);
    attn_fused<<<dim3(16, 16, 2), 256, 0, stream>>>(qh, kh, vt, at);
    gemm_o<<<dim3(8, 64), 256, 0, stream>>>(at, Wob, bo, (float*)d_out);
}